// Round 8
// baseline (14667.418 us; speedup 1.0000x reference)
//
#include <hip/hip_runtime.h>
#include <hip/hip_bf16.h>

#define DIM 768
#define NH 12
#define BB 4
#define LL 1024
#define MM 4096
#define HID 3072

typedef short short8 __attribute__((ext_vector_type(8)));
typedef float f32x4 __attribute__((ext_vector_type(4)));

// f32 -> bf16 bits, round-to-nearest-even (finite inputs)
static __device__ __forceinline__ unsigned short f2bu(float f) {
    unsigned u = __float_as_uint(f);
    u += 0x7fffu + ((u >> 16) & 1u);
    return (unsigned short)(u >> 16);
}

// ---------------- LayerNorm: f32 row of 768 -> bf16(ushort) out ----------------
__global__ __launch_bounds__(256) void ln_kernel(const float* __restrict__ in,
                                                 const float* __restrict__ g,
                                                 const float* __restrict__ bta,
                                                 unsigned short* __restrict__ out) {
    __shared__ float red[8];
    int row = blockIdx.x;
    int tid = threadIdx.x;
    float v[3];
    float s = 0.f, s2 = 0.f;
#pragma unroll
    for (int i = 0; i < 3; ++i) {
        int c = tid + i*256;
        float x = in[(size_t)row*DIM + c];
        v[i] = x; s += x; s2 += x*x;
    }
#pragma unroll
    for (int off = 32; off; off >>= 1) { s += __shfl_down(s, off); s2 += __shfl_down(s2, off); }
    int wv = tid >> 6;
    if ((tid & 63) == 0) { red[wv] = s; red[4+wv] = s2; }
    __syncthreads();
    if (tid == 0) {
        float a = red[0]+red[1]+red[2]+red[3];
        float b = red[4]+red[5]+red[6]+red[7];
        red[0] = a * (1.f/DIM);
        red[4] = b * (1.f/DIM);
    }
    __syncthreads();
    float mu = red[0];
    float var = red[4] - mu*mu;
    float inv = rsqrtf(var + 1e-5f);
#pragma unroll
    for (int i = 0; i < 3; ++i) {
        int c = tid + i*256;
        out[(size_t)row*DIM + c] = f2bu((v[i]-mu)*inv*g[c] + bta[c]);
    }
}

// ---------------- MFMA NT GEMM: A (M x K) bf16-bits, W (N x K) f32 ----------------
// EPI: 0 = bias (f32 out), 2 = bias + exact GELU (bf16 out), 3 = bias + f32 residual (f32 out)
template<int EPI>
__global__ __launch_bounds__(256) void gemm_mfma(const unsigned short* __restrict__ A,
                                                 const float* __restrict__ W,
                                                 const float* __restrict__ bias,
                                                 const float* __restrict__ res,
                                                 void* __restrict__ out,
                                                 int N, int K) {
    __shared__ unsigned short As[128][40];   // pad 32->40: row stride 80 B (16B-mult, 2-way banks)
    __shared__ unsigned short Bs[128][40];
    int tid = threadIdx.x;
    int m0 = blockIdx.y * 128, n0 = blockIdx.x * 128;
    int wave = tid >> 6, lane = tid & 63;
    int wr = wave >> 1, wc = wave & 1;       // 2x2 wave grid, each 64x64
    int lr = lane & 15, kg = lane >> 4;
    f32x4 acc[4][4] = {};
    int ar = tid >> 2, ac = (tid & 3) * 8;   // staging: thread -> (row, 8-elem chunk)

    for (int kt = 0; kt < K; kt += 32) {
        __syncthreads();
        *(int4*)&As[ar][ac]    = *(const int4*)&A[(size_t)(m0+ar)*K + kt + ac];
        *(int4*)&As[ar+64][ac] = *(const int4*)&A[(size_t)(m0+ar+64)*K + kt + ac];
#pragma unroll
        for (int h = 0; h < 2; ++h) {
            int r = ar + h*64;
            const float* wp = &W[(size_t)(n0+r)*K + kt + ac];
            float4 w0 = *(const float4*)wp;
            float4 w1 = *(const float4*)(wp + 4);
            short8 wb;
            wb[0]=f2bu(w0.x); wb[1]=f2bu(w0.y); wb[2]=f2bu(w0.z); wb[3]=f2bu(w0.w);
            wb[4]=f2bu(w1.x); wb[5]=f2bu(w1.y); wb[6]=f2bu(w1.z); wb[7]=f2bu(w1.w);
            *(short8*)&Bs[r][ac] = wb;
        }
        __syncthreads();
        short8 af[4], bg[4];
#pragma unroll
        for (int m = 0; m < 4; ++m) af[m] = *(const short8*)&As[wr*64 + m*16 + lr][kg*8];
#pragma unroll
        for (int n = 0; n < 4; ++n) bg[n] = *(const short8*)&Bs[wc*64 + n*16 + lr][kg*8];
#pragma unroll
        for (int m = 0; m < 4; ++m)
#pragma unroll
            for (int n = 0; n < 4; ++n)
                acc[m][n] = __builtin_amdgcn_mfma_f32_16x16x32_bf16(af[m], bg[n], acc[m][n], 0, 0, 0);
    }

#pragma unroll
    for (int m = 0; m < 4; ++m) {
#pragma unroll
        for (int n = 0; n < 4; ++n) {
            int col = n0 + wc*64 + n*16 + lr;
            float bcol = bias[col];
#pragma unroll
            for (int j = 0; j < 4; ++j) {
                int row = m0 + wr*64 + m*16 + kg*4 + j;   // C/D: col=lane&15, row=(lane>>4)*4+j
                float v = acc[m][n][j] + bcol;
                if (EPI == 3) v += res[(size_t)row*N + col];
                if (EPI == 2) {
                    v = 0.5f*v*(1.f + erff(v*0.70710678118654752f));
                    ((unsigned short*)out)[(size_t)row*N + col] = f2bu(v);
                } else {
                    ((float*)out)[(size_t)row*N + col] = v;
                }
            }
        }
    }
}

// ---------------- RoPE in-place on q,k sections of qkv (f32) ----------------
__global__ __launch_bounds__(256) void rope_kernel(float* __restrict__ qkv) {
    int idx = blockIdx.x*256 + threadIdx.x;   // over MM*NH*32
    int j  = idx & 31;
    int n  = (idx >> 5) % NH;
    int t  = idx / (32*NH);
    int l  = t & (LL-1);
    int pos = (j < 16) ? (l & 31) : (l >> 5);
    int fi = j & 15;
    float freq = expf(-(float)fi * 0.0625f * 9.210340371976184f); // 10000^{-fi/16}
    float ang = (float)pos * freq;
    float sn, cs;
    sincosf(ang, &sn, &cs);
    size_t base = (size_t)t*2304 + (size_t)n*64 + 2*j;
#pragma unroll
    for (int s = 0; s < 2; ++s) {
        float x0 = qkv[base], x1 = qkv[base+1];
        qkv[base]   = x0*cs - x1*sn;
        qkv[base+1] = x0*sn + x1*cs;
        base += 768;
    }
}

// ---------------- attention: block = (b, head, 8 q-rows) ----------------
__global__ __launch_bounds__(256) void attn_kernel(const float* __restrict__ qkv,
                                                   const float* __restrict__ relh,
                                                   const float* __restrict__ relw,
                                                   unsigned short* __restrict__ out) {
    __shared__ float Qs[8][65];
    __shared__ float Ks[64][65];
    __shared__ float rbh[8][33];
    __shared__ float rbw[8][33];
    __shared__ float Ps[8][1024];
    int qt = blockIdx.x, n = blockIdx.y, b = blockIdx.z;
    int tid = threadIdx.x;
    size_t qb = (size_t)b * LL * 2304;

    for (int i = tid; i < 8*64; i += 256) {
        int q = i >> 6, d = i & 63;
        Qs[q][d] = qkv[qb + (size_t)(qt*8 + q)*2304 + n*64 + d];
    }
    __syncthreads();

    int q = tid >> 5, c = tid & 31;           // q-row 0..7, lane-in-group 0..31
    int qh = qt >> 2, qw = (qt & 3)*8 + q;
    {
        float ah = 0.f, aw = 0.f;
        const float* rh = relh + (size_t)(qh - c + 31)*64;
        const float* rw = relw + (size_t)(qw - c + 31)*64;
        for (int d = 0; d < 64; ++d) { float qd = Qs[q][d]; ah += qd*rh[d]; aw += qd*rw[d]; }
        rbh[q][c] = ah; rbw[q][c] = aw;
    }
    __syncthreads();

    float rbwq = rbw[q][c];                   // this thread's k's all have kw == c
    float p[32];
#pragma unroll
    for (int kt = 0; kt < 16; ++kt) {
        __syncthreads();
        for (int i = tid; i < 64*64; i += 256) {
            int r = i >> 6, d = i & 63;
            Ks[r][d] = qkv[qb + (size_t)(kt*64 + r)*2304 + 768 + n*64 + d];
        }
        __syncthreads();
        float a0 = 0.f, a1 = 0.f;
        for (int d = 0; d < 64; ++d) {
            float qd = Qs[q][d];
            a0 += qd * Ks[c][d];
            a1 += qd * Ks[c+32][d];
        }
        p[kt*2]   = a0*0.125f + rbh[q][kt*2]   + rbwq;   // k = 64*kt + c
        p[kt*2+1] = a1*0.125f + rbh[q][kt*2+1] + rbwq;   // k = 64*kt + 32 + c
    }

    float m = -1e30f;
#pragma unroll
    for (int j = 0; j < 32; ++j) m = fmaxf(m, p[j]);
#pragma unroll
    for (int off = 16; off; off >>= 1) m = fmaxf(m, __shfl_xor(m, off, 32));
    float s = 0.f;
#pragma unroll
    for (int j = 0; j < 32; ++j) { p[j] = __expf(p[j] - m); s += p[j]; }
#pragma unroll
    for (int off = 16; off; off >>= 1) s += __shfl_xor(s, off, 32);
    float inv = 1.f / s;
#pragma unroll
    for (int j = 0; j < 32; ++j) Ps[q][c + 32*j] = p[j];
    __syncthreads();

    int dg = tid & 31;                         // same q as above
    const float* vrow = qkv + qb + 1536 + n*64 + dg*2;
    float o0 = 0.f, o1 = 0.f;
#pragma unroll 4
    for (int k = 0; k < 1024; ++k) {
        float pk = Ps[q][k];
        float2 v = *(const float2*)&vrow[(size_t)k*2304];
        o0 += pk*v.x; o1 += pk*v.y;
    }
    size_t orow = ((size_t)b*LL + qt*8 + q)*DIM + n*64 + dg*2;
    out[orow]   = f2bu(o0*inv);
    out[orow+1] = f2bu(o1*inv);
}

extern "C" void kernel_launch(void* const* d_in, const int* in_sizes, int n_in,
                              void* d_out, int out_size, void* d_ws, size_t ws_size,
                              hipStream_t stream) {
    const float* x      = (const float*)d_in[0];
    const float* ln1w   = (const float*)d_in[1];
    const float* ln1b   = (const float*)d_in[2];
    const float* w_qkv  = (const float*)d_in[3];
    const float* b_qkv  = (const float*)d_in[4];
    const float* w_proj = (const float*)d_in[5];
    const float* b_proj = (const float*)d_in[6];
    const float* relh   = (const float*)d_in[7];
    const float* relw   = (const float*)d_in[8];
    const float* ln2w   = (const float*)d_in[9];
    const float* ln2b   = (const float*)d_in[10];
    const float* w_fc1  = (const float*)d_in[11];
    const float* b_fc1  = (const float*)d_in[12];
    const float* w_fc2  = (const float*)d_in[13];
    const float* b_fc2  = (const float*)d_in[14];

    char* ws = (char*)d_ws;
    unsigned short* xn   = (unsigned short*)(ws);              // 6,291,456 B (4096x768 bf16)
    float*          qkv  = (float*)(ws + 6291456);             // 37,748,736 B (4096x2304 f32)
    unsigned short* aout = (unsigned short*)(ws + 44040192);   // 6,291,456 B (4096x768 bf16)
    float*          x2   = (float*)(ws + 50331648);            // 12,582,912 B (4096x768 f32)
    unsigned short* fc1h = (unsigned short*)(ws + 6291456);    // reuse qkv region (4096x3072 bf16)

    // 1. LN1: x(f32) -> xn(bf16)
    ln_kernel<<<MM, 256, 0, stream>>>(x, ln1w, ln1b, xn);
    // 2. QKV GEMM (4096 x 2304, K=768) + bias -> qkv f32
    gemm_mfma<0><<<dim3(18, 32), 256, 0, stream>>>(xn, w_qkv, b_qkv, nullptr, qkv, 2304, 768);
    // 3. RoPE in place on q, k
    rope_kernel<<<6144, 256, 0, stream>>>(qkv);
    // 4. attention -> aout bf16
    attn_kernel<<<dim3(128, NH, BB), 256, 0, stream>>>(qkv, relh, relw, aout);
    // 5. proj GEMM + bias + residual(x f32) -> x2 f32
    gemm_mfma<3><<<dim3(6, 32), 256, 0, stream>>>(aout, w_proj, b_proj, x, x2, 768, 768);
    // 6. LN2: x2 -> xn
    ln_kernel<<<MM, 256, 0, stream>>>(x2, ln2w, ln2b, xn);
    // 7. fc1 GEMM + bias + GELU -> fc1h bf16
    gemm_mfma<2><<<dim3(24, 32), 256, 0, stream>>>(xn, w_fc1, b_fc1, nullptr, fc1h, HID, 768);
    // 8. fc2 GEMM (K=3072) + bias + residual(x2) -> d_out f32
    gemm_mfma<3><<<dim3(6, 32), 256, 0, stream>>>(fc1h, w_fc2, b_fc2, x2, (float*)d_out, 768, 3072);
}

// Round 9
// 1420.225 us; speedup vs baseline: 10.3275x; 10.3275x over previous
//
#include <hip/hip_runtime.h>
#include <hip/hip_bf16.h>

#define DIM 768
#define NH 12
#define BB 4
#define LL 1024
#define MM 4096
#define HID 3072

typedef short short8 __attribute__((ext_vector_type(8)));
typedef float f32x4 __attribute__((ext_vector_type(4)));

// f32 -> bf16 bits, round-to-nearest-even (finite inputs)
static __device__ __forceinline__ unsigned short f2bu(float f) {
    unsigned u = __float_as_uint(f);
    u += 0x7fffu + ((u >> 16) & 1u);
    return (unsigned short)(u >> 16);
}

// ---------------- LayerNorm: f32 row of 768 -> bf16(ushort) out ----------------
__global__ __launch_bounds__(256) void ln_kernel(const float* __restrict__ in,
                                                 const float* __restrict__ g,
                                                 const float* __restrict__ bta,
                                                 unsigned short* __restrict__ out) {
    __shared__ float red[8];
    int row = blockIdx.x;
    int tid = threadIdx.x;
    float v[3];
    float s = 0.f, s2 = 0.f;
#pragma unroll
    for (int i = 0; i < 3; ++i) {
        int c = tid + i*256;
        float x = in[(size_t)row*DIM + c];
        v[i] = x; s += x; s2 += x*x;
    }
#pragma unroll
    for (int off = 32; off; off >>= 1) { s += __shfl_down(s, off); s2 += __shfl_down(s2, off); }
    int wv = tid >> 6;
    if ((tid & 63) == 0) { red[wv] = s; red[4+wv] = s2; }
    __syncthreads();
    if (tid == 0) {
        float a = red[0]+red[1]+red[2]+red[3];
        float b = red[4]+red[5]+red[6]+red[7];
        red[0] = a * (1.f/DIM);
        red[4] = b * (1.f/DIM);
    }
    __syncthreads();
    float mu = red[0];
    float var = red[4] - mu*mu;
    float inv = rsqrtf(var + 1e-5f);
#pragma unroll
    for (int i = 0; i < 3; ++i) {
        int c = tid + i*256;
        out[(size_t)row*DIM + c] = f2bu((v[i]-mu)*inv*g[c] + bta[c]);
    }
}

// ---------------- MFMA NT GEMM: A (M x K) bf16-bits, W (N x K) f32 ----------------
// EPI: 0 = bias (f32 out), 2 = bias + exact GELU (bf16 out), 3 = bias + f32 residual (f32 out)
template<int EPI>
__global__ __launch_bounds__(256) void gemm_mfma(const unsigned short* __restrict__ A,
                                                 const float* __restrict__ W,
                                                 const float* __restrict__ bias,
                                                 const float* __restrict__ res,
                                                 void* __restrict__ out,
                                                 int N, int K) {
    __shared__ unsigned short As[128][40];   // pad 32->40: row stride 80 B (16B-mult, 2-way banks)
    __shared__ unsigned short Bs[128][40];
    int tid = threadIdx.x;
    int m0 = blockIdx.y * 128, n0 = blockIdx.x * 128;
    int wave = tid >> 6, lane = tid & 63;
    int wr = wave >> 1, wc = wave & 1;       // 2x2 wave grid, each 64x64
    int lr = lane & 15, kg = lane >> 4;
    f32x4 acc[4][4] = {};
    int ar = tid >> 2, ac = (tid & 3) * 8;   // staging: thread -> (row, 8-elem chunk)

    for (int kt = 0; kt < K; kt += 32) {
        __syncthreads();
        *(int4*)&As[ar][ac]    = *(const int4*)&A[(size_t)(m0+ar)*K + kt + ac];
        *(int4*)&As[ar+64][ac] = *(const int4*)&A[(size_t)(m0+ar+64)*K + kt + ac];
#pragma unroll
        for (int h = 0; h < 2; ++h) {
            int r = ar + h*64;
            const float* wp = &W[(size_t)(n0+r)*K + kt + ac];
            float4 w0 = *(const float4*)wp;
            float4 w1 = *(const float4*)(wp + 4);
            short8 wb;
            wb[0]=f2bu(w0.x); wb[1]=f2bu(w0.y); wb[2]=f2bu(w0.z); wb[3]=f2bu(w0.w);
            wb[4]=f2bu(w1.x); wb[5]=f2bu(w1.y); wb[6]=f2bu(w1.z); wb[7]=f2bu(w1.w);
            *(short8*)&Bs[r][ac] = wb;
        }
        __syncthreads();
        short8 af[4], bg[4];
#pragma unroll
        for (int m = 0; m < 4; ++m) af[m] = *(const short8*)&As[wr*64 + m*16 + lr][kg*8];
#pragma unroll
        for (int n = 0; n < 4; ++n) bg[n] = *(const short8*)&Bs[wc*64 + n*16 + lr][kg*8];
#pragma unroll
        for (int m = 0; m < 4; ++m)
#pragma unroll
            for (int n = 0; n < 4; ++n)
                acc[m][n] = __builtin_amdgcn_mfma_f32_16x16x32_bf16(af[m], bg[n], acc[m][n], 0, 0, 0);
    }

#pragma unroll
    for (int m = 0; m < 4; ++m) {
#pragma unroll
        for (int n = 0; n < 4; ++n) {
            int col = n0 + wc*64 + n*16 + lr;
            float bcol = bias[col];
#pragma unroll
            for (int j = 0; j < 4; ++j) {
                int row = m0 + wr*64 + m*16 + kg*4 + j;   // C/D: col=lane&15, row=(lane>>4)*4+j
                float v = acc[m][n][j] + bcol;
                if (EPI == 3) v += res[(size_t)row*N + col];
                if (EPI == 2) {
                    v = 0.5f*v*(1.f + erff(v*0.70710678118654752f));
                    ((unsigned short*)out)[(size_t)row*N + col] = f2bu(v);
                } else {
                    ((float*)out)[(size_t)row*N + col] = v;
                }
            }
        }
    }
}

// ---------------- RoPE in-place on q,k sections of qkv (f32) ----------------
__global__ __launch_bounds__(256) void rope_kernel(float* __restrict__ qkv) {
    int idx = blockIdx.x*256 + threadIdx.x;   // over MM*NH*32
    int j  = idx & 31;
    int n  = (idx >> 5) % NH;
    int t  = idx / (32*NH);
    int l  = t & (LL-1);
    int pos = (j < 16) ? (l & 31) : (l >> 5);
    int fi = j & 15;
    float freq = expf(-(float)fi * 0.0625f * 9.210340371976184f); // 10000^{-fi/16}
    float ang = (float)pos * freq;
    float sn, cs;
    sincosf(ang, &sn, &cs);
    size_t base = (size_t)t*2304 + (size_t)n*64 + 2*j;
#pragma unroll
    for (int s = 0; s < 2; ++s) {
        float x0 = qkv[base], x1 = qkv[base+1];
        qkv[base]   = x0*cs - x1*sn;
        qkv[base+1] = x0*sn + x1*cs;
        base += 768;
    }
}

// ---------------- attention: block = (b, head, 8 q-rows) ----------------
// Scores go straight to LDS (no per-thread score array -> no scratch spills).
__global__ __launch_bounds__(256) void attn_kernel(const float* __restrict__ qkv,
                                                   const float* __restrict__ relh,
                                                   const float* __restrict__ relw,
                                                   unsigned short* __restrict__ out) {
    __shared__ float Qs[8][65];
    __shared__ float Ks[64][65];
    __shared__ float rbh[8][33];
    __shared__ float rbw[8][33];
    __shared__ float Ps[8][1024];
    int qt = blockIdx.x, n = blockIdx.y, b = blockIdx.z;
    int tid = threadIdx.x;
    size_t qb = (size_t)b * LL * 2304;

    for (int i = tid; i < 8*64; i += 256) {
        int q = i >> 6, d = i & 63;
        Qs[q][d] = qkv[qb + (size_t)(qt*8 + q)*2304 + n*64 + d];
    }
    __syncthreads();

    int q = tid >> 5, c = tid & 31;           // q-row 0..7, lane-in-group 0..31
    int qh = qt >> 2, qw = (qt & 3)*8 + q;
    {
        float ah = 0.f, aw = 0.f;
        const float* rh = relh + (size_t)(qh - c + 31)*64;
        const float* rw = relw + (size_t)(qw - c + 31)*64;
        for (int d = 0; d < 64; ++d) { float qd = Qs[q][d]; ah += qd*rh[d]; aw += qd*rw[d]; }
        rbh[q][c] = ah; rbw[q][c] = aw;
    }
    __syncthreads();

    float rbwq = rbw[q][c];                   // this thread's k's all have kw == c
#pragma unroll 1
    for (int kt = 0; kt < 16; ++kt) {
        __syncthreads();
        for (int i = tid; i < 64*64; i += 256) {
            int r = i >> 6, d = i & 63;
            Ks[r][d] = qkv[qb + (size_t)(kt*64 + r)*2304 + 768 + n*64 + d];
        }
        __syncthreads();
        float a0 = 0.f, a1 = 0.f;
        for (int d = 0; d < 64; ++d) {
            float qd = Qs[q][d];
            a0 += qd * Ks[c][d];
            a1 += qd * Ks[c+32][d];
        }
        // score k = 64*kt + c  (kh = 2kt, kw = c)   -> column c + 32*(2kt)
        // score k = 64*kt+32+c (kh = 2kt+1, kw = c) -> column c + 32*(2kt+1)
        Ps[q][kt*64 + c]      = a0*0.125f + rbh[q][kt*2]   + rbwq;
        Ps[q][kt*64 + 32 + c] = a1*0.125f + rbh[q][kt*2+1] + rbwq;
    }

    // softmax over row q: lane c owns columns {c + 32*j}, exactly what it wrote
    float m = -1e30f;
#pragma unroll
    for (int j = 0; j < 32; ++j) m = fmaxf(m, Ps[q][c + 32*j]);
#pragma unroll
    for (int off = 16; off; off >>= 1) m = fmaxf(m, __shfl_xor(m, off, 32));
    float s = 0.f;
#pragma unroll
    for (int j = 0; j < 32; ++j) {
        float e = __expf(Ps[q][c + 32*j] - m);
        Ps[q][c + 32*j] = e;
        s += e;
    }
#pragma unroll
    for (int off = 16; off; off >>= 1) s += __shfl_xor(s, off, 32);
    float inv = 1.f / s;
    __syncthreads();

    int dg = tid & 31;                         // same q as above
    const float* vrow = qkv + qb + 1536 + n*64 + dg*2;
    float o0 = 0.f, o1 = 0.f;
#pragma unroll 4
    for (int k = 0; k < 1024; ++k) {
        float pk = Ps[q][k];
        float2 v = *(const float2*)&vrow[(size_t)k*2304];
        o0 += pk*v.x; o1 += pk*v.y;
    }
    size_t orow = ((size_t)b*LL + qt*8 + q)*DIM + n*64 + dg*2;
    out[orow]   = f2bu(o0*inv);
    out[orow+1] = f2bu(o1*inv);
}

extern "C" void kernel_launch(void* const* d_in, const int* in_sizes, int n_in,
                              void* d_out, int out_size, void* d_ws, size_t ws_size,
                              hipStream_t stream) {
    const float* x      = (const float*)d_in[0];
    const float* ln1w   = (const float*)d_in[1];
    const float* ln1b   = (const float*)d_in[2];
    const float* w_qkv  = (const float*)d_in[3];
    const float* b_qkv  = (const float*)d_in[4];
    const float* w_proj = (const float*)d_in[5];
    const float* b_proj = (const float*)d_in[6];
    const float* relh   = (const float*)d_in[7];
    const float* relw   = (const float*)d_in[8];
    const float* ln2w   = (const float*)d_in[9];
    const float* ln2b   = (const float*)d_in[10];
    const float* w_fc1  = (const float*)d_in[11];
    const float* b_fc1  = (const float*)d_in[12];
    const float* w_fc2  = (const float*)d_in[13];
    const float* b_fc2  = (const float*)d_in[14];

    char* ws = (char*)d_ws;
    unsigned short* xn   = (unsigned short*)(ws);              // 6,291,456 B (4096x768 bf16)
    float*          qkv  = (float*)(ws + 6291456);             // 37,748,736 B (4096x2304 f32)
    unsigned short* aout = (unsigned short*)(ws + 44040192);   // 6,291,456 B (4096x768 bf16)
    float*          x2   = (float*)(ws + 50331648);            // 12,582,912 B (4096x768 f32)
    unsigned short* fc1h = (unsigned short*)(ws + 6291456);    // reuse qkv region (4096x3072 bf16)

    // 1. LN1: x(f32) -> xn(bf16)
    ln_kernel<<<MM, 256, 0, stream>>>(x, ln1w, ln1b, xn);
    // 2. QKV GEMM (4096 x 2304, K=768) + bias -> qkv f32
    gemm_mfma<0><<<dim3(18, 32), 256, 0, stream>>>(xn, w_qkv, b_qkv, nullptr, qkv, 2304, 768);
    // 3. RoPE in place on q, k
    rope_kernel<<<6144, 256, 0, stream>>>(qkv);
    // 4. attention -> aout bf16
    attn_kernel<<<dim3(128, NH, BB), 256, 0, stream>>>(qkv, relh, relw, aout);
    // 5. proj GEMM + bias + residual(x f32) -> x2 f32
    gemm_mfma<3><<<dim3(6, 32), 256, 0, stream>>>(aout, w_proj, b_proj, x, x2, 768, 768);
    // 6. LN2: x2 -> xn
    ln_kernel<<<MM, 256, 0, stream>>>(x2, ln2w, ln2b, xn);
    // 7. fc1 GEMM + bias + GELU -> fc1h bf16
    gemm_mfma<2><<<dim3(24, 32), 256, 0, stream>>>(xn, w_fc1, b_fc1, nullptr, fc1h, HID, 768);
    // 8. fc2 GEMM (K=3072) + bias + residual(x2) -> d_out f32
    gemm_mfma<3><<<dim3(6, 32), 256, 0, stream>>>(fc1h, w_fc2, b_fc2, x2, (float*)d_out, 768, 3072);
}

// Round 10
// 531.421 us; speedup vs baseline: 27.6004x; 2.6725x over previous
//
#include <hip/hip_runtime.h>
#include <hip/hip_bf16.h>

#define DIM 768
#define NH 12
#define BB 4
#define LL 1024
#define MM 4096
#define HID 3072

typedef short short8 __attribute__((ext_vector_type(8)));
typedef float f32x4 __attribute__((ext_vector_type(4)));

// f32 -> bf16 bits, round-to-nearest-even (finite inputs)
static __device__ __forceinline__ unsigned short f2bu(float f) {
    unsigned u = __float_as_uint(f);
    u += 0x7fffu + ((u >> 16) & 1u);
    return (unsigned short)(u >> 16);
}
static __device__ __forceinline__ float bu2f(unsigned short u) {
    return __uint_as_float((unsigned)u << 16);
}

// ---------------- LayerNorm: f32 row of 768 -> bf16(ushort) out ----------------
__global__ __launch_bounds__(256) void ln_kernel(const float* __restrict__ in,
                                                 const float* __restrict__ g,
                                                 const float* __restrict__ bta,
                                                 unsigned short* __restrict__ out) {
    __shared__ float red[8];
    int row = blockIdx.x;
    int tid = threadIdx.x;
    float v[3];
    float s = 0.f, s2 = 0.f;
#pragma unroll
    for (int i = 0; i < 3; ++i) {
        int c = tid + i*256;
        float x = in[(size_t)row*DIM + c];
        v[i] = x; s += x; s2 += x*x;
    }
#pragma unroll
    for (int off = 32; off; off >>= 1) { s += __shfl_down(s, off); s2 += __shfl_down(s2, off); }
    int wv = tid >> 6;
    if ((tid & 63) == 0) { red[wv] = s; red[4+wv] = s2; }
    __syncthreads();
    if (tid == 0) {
        float a = red[0]+red[1]+red[2]+red[3];
        float b = red[4]+red[5]+red[6]+red[7];
        red[0] = a * (1.f/DIM);
        red[4] = b * (1.f/DIM);
    }
    __syncthreads();
    float mu = red[0];
    float var = red[4] - mu*mu;
    float inv = rsqrtf(var + 1e-5f);
#pragma unroll
    for (int i = 0; i < 3; ++i) {
        int c = tid + i*256;
        out[(size_t)row*DIM + c] = f2bu((v[i]-mu)*inv*g[c] + bta[c]);
    }
}

// ---------------- MFMA NT GEMM: A (M x K) bf16-bits, W (N x K) f32 ----------------
// EPI: 0 = bias (f32 out), 2 = bias + exact GELU (bf16 out), 3 = bias + f32 residual (f32 out)
template<int EPI>
__global__ __launch_bounds__(256) void gemm_mfma(const unsigned short* __restrict__ A,
                                                 const float* __restrict__ W,
                                                 const float* __restrict__ bias,
                                                 const float* __restrict__ res,
                                                 void* __restrict__ out,
                                                 int N, int K) {
    __shared__ unsigned short As[128][40];   // pad 32->40: row stride 80 B (16B-mult, 2-way banks)
    __shared__ unsigned short Bs[128][40];
    int tid = threadIdx.x;
    int m0 = blockIdx.y * 128, n0 = blockIdx.x * 128;
    int wave = tid >> 6, lane = tid & 63;
    int wr = wave >> 1, wc = wave & 1;       // 2x2 wave grid, each 64x64
    int lr = lane & 15, kg = lane >> 4;
    f32x4 acc[4][4] = {};
    int ar = tid >> 2, ac = (tid & 3) * 8;   // staging: thread -> (row, 8-elem chunk)

    for (int kt = 0; kt < K; kt += 32) {
        __syncthreads();
        *(int4*)&As[ar][ac]    = *(const int4*)&A[(size_t)(m0+ar)*K + kt + ac];
        *(int4*)&As[ar+64][ac] = *(const int4*)&A[(size_t)(m0+ar+64)*K + kt + ac];
#pragma unroll
        for (int h = 0; h < 2; ++h) {
            int r = ar + h*64;
            const float* wp = &W[(size_t)(n0+r)*K + kt + ac];
            float4 w0 = *(const float4*)wp;
            float4 w1 = *(const float4*)(wp + 4);
            short8 wb;
            wb[0]=f2bu(w0.x); wb[1]=f2bu(w0.y); wb[2]=f2bu(w0.z); wb[3]=f2bu(w0.w);
            wb[4]=f2bu(w1.x); wb[5]=f2bu(w1.y); wb[6]=f2bu(w1.z); wb[7]=f2bu(w1.w);
            *(short8*)&Bs[r][ac] = wb;
        }
        __syncthreads();
        short8 af[4], bg[4];
#pragma unroll
        for (int m = 0; m < 4; ++m) af[m] = *(const short8*)&As[wr*64 + m*16 + lr][kg*8];
#pragma unroll
        for (int n = 0; n < 4; ++n) bg[n] = *(const short8*)&Bs[wc*64 + n*16 + lr][kg*8];
#pragma unroll
        for (int m = 0; m < 4; ++m)
#pragma unroll
            for (int n = 0; n < 4; ++n)
                acc[m][n] = __builtin_amdgcn_mfma_f32_16x16x32_bf16(af[m], bg[n], acc[m][n], 0, 0, 0);
    }

#pragma unroll
    for (int m = 0; m < 4; ++m) {
#pragma unroll
        for (int n = 0; n < 4; ++n) {
            int col = n0 + wc*64 + n*16 + lr;
            float bcol = bias[col];
#pragma unroll
            for (int j = 0; j < 4; ++j) {
                int row = m0 + wr*64 + m*16 + kg*4 + j;   // C/D: col=lane&15, row=(lane>>4)*4+j
                float v = acc[m][n][j] + bcol;
                if (EPI == 3) v += res[(size_t)row*N + col];
                if (EPI == 2) {
                    v = 0.5f*v*(1.f + erff(v*0.70710678118654752f));
                    ((unsigned short*)out)[(size_t)row*N + col] = f2bu(v);
                } else {
                    ((float*)out)[(size_t)row*N + col] = v;
                }
            }
        }
    }
}

// ---------------- qkv f32 -> per-head bf16 q/k/v with fused RoPE on q,k ----------------
// qb/kb/vb layout: [B][NH][L][64]
__global__ __launch_bounds__(256) void qkv_cvt(const float* __restrict__ qkv,
                                               unsigned short* __restrict__ qb,
                                               unsigned short* __restrict__ kb,
                                               unsigned short* __restrict__ vb) {
    int idx = blockIdx.x*256 + threadIdx.x;      // over 4096*1152 element-pairs
    int t  = idx / 1152;
    int cp = idx - t*1152;
    int col = cp*2;
    int s = col / 768;
    int wi = col - s*768;
    int n = wi >> 6, d = wi & 63;
    float2 v2 = *(const float2*)&qkv[(size_t)t*2304 + col];
    int l = t & (LL-1);
    if (s < 2) {
        int j = d >> 1;                          // pair index 0..31
        int pos = (j < 16) ? (l & 31) : (l >> 5);
        float freq = expf(-(float)(j & 15) * 0.0625f * 9.210340371976184f);
        float ang = (float)pos * freq;
        float sn, cs;
        sincosf(ang, &sn, &cs);
        float x0 = v2.x, x1 = v2.y;
        v2.x = x0*cs - x1*sn;
        v2.y = x0*sn + x1*cs;
    }
    unsigned short* dst = (s == 0) ? qb : (s == 1) ? kb : vb;
    int b = t >> 10;
    unsigned pk = (unsigned)f2bu(v2.x) | ((unsigned)f2bu(v2.y) << 16);
    *(unsigned*)&dst[((size_t)(b*NH + n)*LL + l)*64 + d] = pk;
}

// ---------------- MFMA flash attention: block = (b, head, 64 q-rows) ----------------
__global__ __launch_bounds__(256) void attn_mfma(const unsigned short* __restrict__ qb,
                                                 const unsigned short* __restrict__ kb,
                                                 const unsigned short* __restrict__ vb,
                                                 const float* __restrict__ relh,
                                                 const float* __restrict__ relw,
                                                 unsigned short* __restrict__ out) {
    __shared__ unsigned short Kb[64][72];     // K tile [k][d], stride 144B (16B-mult)
    __shared__ unsigned short Vt[64][72];     // V^T tile [d][k]
    __shared__ unsigned short Pb[4][16][72];  // per-wave P bounce [q][k]
    __shared__ float rbh[64][36];             // q x kh bias (padded rows)
    __shared__ float rbw[64][36];             // q x kw bias
    __shared__ float sl[128];                 // [0:64) per-tile scale, [64:128) 1/l
    int qt = blockIdx.x, n = blockIdx.y, b = blockIdx.z;
    int tid = threadIdx.x;
    int w = tid >> 6, lane = tid & 63;
    int lr = lane & 15, kg = lane >> 4;
    size_t hb = ((size_t)b*NH + n) * (LL*64);

    // --- rel-pos bias tables from roped bf16 q ---
    {
        int q = tid >> 2, g = tid & 3;
        int qrow = qt*64 + q;
        int qh = qrow >> 5, qw = qrow & 31;
        const unsigned short* qr = qb + hb + (size_t)qrow*64;
        float ah[8] = {}, aw[8] = {};
        for (int d = 0; d < 64; ++d) {
            float qd = bu2f(qr[d]);
#pragma unroll
            for (int i = 0; i < 8; ++i) {
                ah[i] += qd * relh[(size_t)(qh - (g*8+i) + 31)*64 + d];
                aw[i] += qd * relw[(size_t)(qw - (g*8+i) + 31)*64 + d];
            }
        }
#pragma unroll
        for (int i = 0; i < 8; ++i) { rbh[q][g*8+i] = ah[i]; rbw[q][g*8+i] = aw[i]; }
    }

    // --- Q fragments (B-operand; rows w*16+lr), held in regs all kernel ---
    const unsigned short* qfr = qb + hb + (size_t)(qt*64 + w*16 + lr)*64;
    short8 qf0 = *(const short8*)(qfr + kg*8);
    short8 qf1 = *(const short8*)(qfr + 32 + kg*8);

    f32x4 o[4] = {};            // [dsub]; component j <-> q = w*16+kg*4+j; col d = dsub*16+lr
    float mR = -1e30f, lR = 0.f;

    __syncthreads();            // rb tables ready

    for (int kt = 0; kt < 16; ++kt) {
        __syncthreads();        // previous tile's LDS reads done
        {   // stage K tile + V^T tile
            int r = tid >> 3, c8 = (tid & 7) * 8;
            const unsigned short* kptr = kb + hb + (size_t)(kt*64)*64;
            *(short8*)&Kb[r][c8]    = *(const short8*)(kptr + (size_t)r*64 + c8);
            *(short8*)&Kb[r+32][c8] = *(const short8*)(kptr + (size_t)(r+32)*64 + c8);
            const unsigned short* vptr = vb + hb + (size_t)(kt*64)*64;
            short8 v0 = *(const short8*)(vptr + (size_t)r*64 + c8);
            short8 v1 = *(const short8*)(vptr + (size_t)(r+32)*64 + c8);
#pragma unroll
            for (int i = 0; i < 8; ++i) { Vt[c8+i][r] = v0[i]; Vt[c8+i][r+32] = v1[i]; }
        }
        __syncthreads();

        // swapped QK^T: st[ks]; lane's scores all have q = w*16+lr, k = ks*16+kg*4+j
        f32x4 st[4] = {};
#pragma unroll
        for (int ks = 0; ks < 4; ++ks) {
            short8 kf0 = *(const short8*)&Kb[ks*16 + lr][kg*8];
            short8 kf1 = *(const short8*)&Kb[ks*16 + lr][32 + kg*8];
            st[ks] = __builtin_amdgcn_mfma_f32_16x16x32_bf16(kf0, qf0, st[ks], 0, 0, 0);
            st[ks] = __builtin_amdgcn_mfma_f32_16x16x32_bf16(kf1, qf1, st[ks], 0, 0, 0);
        }
        int q = w*16 + lr;
        float rh0 = rbh[q][kt*2], rh1 = rbh[q][kt*2+1];
        f32x4 rw0 = *(const f32x4*)&rbw[q][kg*4];
        f32x4 rw1 = *(const f32x4*)&rbw[q][16 + kg*4];
        float tmax = -1e30f;
#pragma unroll
        for (int ks = 0; ks < 4; ++ks) {
            float rh = (ks < 2) ? rh0 : rh1;
#pragma unroll
            for (int j = 0; j < 4; ++j) {
                float sv = st[ks][j]*0.125f + rh + ((ks & 1) ? rw1[j] : rw0[j]);
                st[ks][j] = sv;
                tmax = fmaxf(tmax, sv);
            }
        }
        tmax = fmaxf(tmax, __shfl_xor(tmax, 16));
        tmax = fmaxf(tmax, __shfl_xor(tmax, 32));
        float mnew = fmaxf(mR, tmax);
        float sc = __expf(mR - mnew);
        float tsum = 0.f;
        unsigned pw0[4], pw1[4];
#pragma unroll
        for (int ks = 0; ks < 4; ++ks) {
            float e0 = __expf(st[ks][0]-mnew), e1 = __expf(st[ks][1]-mnew);
            float e2 = __expf(st[ks][2]-mnew), e3 = __expf(st[ks][3]-mnew);
            tsum += (e0+e1)+(e2+e3);
            pw0[ks] = (unsigned)f2bu(e0) | ((unsigned)f2bu(e1) << 16);
            pw1[ks] = (unsigned)f2bu(e2) | ((unsigned)f2bu(e3) << 16);
        }
        tsum += __shfl_xor(tsum, 16);
        tsum += __shfl_xor(tsum, 32);
        lR = lR*sc + tsum;
        mR = mnew;
        if (lane < 16) sl[w*16 + lr] = sc;
#pragma unroll
        for (int ks = 0; ks < 4; ++ks)
            *(uint2*)&Pb[w][lr][ks*16 + kg*4] = make_uint2(pw0[ks], pw1[ks]);
        // rescale O by per-row scale (component j <-> q = w*16+kg*4+j)
        f32x4 sc4 = *(const f32x4*)&sl[w*16 + kg*4];
#pragma unroll
        for (int ds = 0; ds < 4; ++ds) o[ds] *= sc4;
        // PV: A = P (rows q via lr), B = V^T (rows d via lr)
        short8 pf0 = *(const short8*)&Pb[w][lr][kg*8];
        short8 pf1 = *(const short8*)&Pb[w][lr][32 + kg*8];
#pragma unroll
        for (int ds = 0; ds < 4; ++ds) {
            short8 vt0 = *(const short8*)&Vt[ds*16 + lr][kg*8];
            short8 vt1 = *(const short8*)&Vt[ds*16 + lr][32 + kg*8];
            o[ds] = __builtin_amdgcn_mfma_f32_16x16x32_bf16(pf0, vt0, o[ds], 0, 0, 0);
            o[ds] = __builtin_amdgcn_mfma_f32_16x16x32_bf16(pf1, vt1, o[ds], 0, 0, 0);
        }
    }

    if (lane < 16) sl[64 + w*16 + lr] = 1.f / lR;
    f32x4 il4 = *(const f32x4*)&sl[64 + w*16 + kg*4];
#pragma unroll
    for (int ds = 0; ds < 4; ++ds)
#pragma unroll
        for (int j = 0; j < 4; ++j) {
            size_t row = (size_t)b*LL + qt*64 + w*16 + kg*4 + j;
            out[row*DIM + n*64 + ds*16 + lr] = f2bu(o[ds][j] * il4[j]);
        }
}

extern "C" void kernel_launch(void* const* d_in, const int* in_sizes, int n_in,
                              void* d_out, int out_size, void* d_ws, size_t ws_size,
                              hipStream_t stream) {
    const float* x      = (const float*)d_in[0];
    const float* ln1w   = (const float*)d_in[1];
    const float* ln1b   = (const float*)d_in[2];
    const float* w_qkv  = (const float*)d_in[3];
    const float* b_qkv  = (const float*)d_in[4];
    const float* w_proj = (const float*)d_in[5];
    const float* b_proj = (const float*)d_in[6];
    const float* relh   = (const float*)d_in[7];
    const float* relw   = (const float*)d_in[8];
    const float* ln2w   = (const float*)d_in[9];
    const float* ln2b   = (const float*)d_in[10];
    const float* w_fc1  = (const float*)d_in[11];
    const float* b_fc1  = (const float*)d_in[12];
    const float* w_fc2  = (const float*)d_in[13];
    const float* b_fc2  = (const float*)d_in[14];

    char* ws = (char*)d_ws;
    unsigned short* xn   = (unsigned short*)(ws);              // [0, 6.29MB) xn / later qb alias target
    float*          qkv  = (float*)(ws + 6291456);             // [6.29, 44.04MB) qkv f32
    unsigned short* aout = (unsigned short*)(ws + 44040192);   // [44.04, 50.33MB)
    float*          x2   = (float*)(ws + 50331648);            // [50.33, 62.91MB)
    unsigned short* fc1h = (unsigned short*)(ws + 6291456);    // reuse qkv region
    // bf16 head-major q/k/v (aliasing dead regions; see liveness below)
    unsigned short* qb   = (unsigned short*)(ws);              // xn dead after QKV GEMM
    unsigned short* kb   = (unsigned short*)(ws + 50331648);   // x2 written only at step 5
    unsigned short* vb   = (unsigned short*)(ws + 56623104);

    // 1. LN1: x -> xn (bf16)
    ln_kernel<<<MM, 256, 0, stream>>>(x, ln1w, ln1b, xn);
    // 2. QKV GEMM -> qkv f32
    gemm_mfma<0><<<dim3(18, 32), 256, 0, stream>>>(xn, w_qkv, b_qkv, nullptr, qkv, 2304, 768);
    // 3. convert+rope: qkv f32 -> qb/kb/vb bf16 (overwrites xn region; xn dead)
    qkv_cvt<<<18432, 256, 0, stream>>>(qkv, qb, kb, vb);
    // 4. MFMA flash attention -> aout bf16
    attn_mfma<<<dim3(16, NH, BB), 256, 0, stream>>>(qb, kb, vb, relh, relw, aout);
    // 5. proj GEMM + bias + residual(x) -> x2 (overwrites kb/vb; dead)
    gemm_mfma<3><<<dim3(6, 32), 256, 0, stream>>>(aout, w_proj, b_proj, x, x2, 768, 768);
    // 6. LN2: x2 -> xn (overwrites qb; dead)
    ln_kernel<<<MM, 256, 0, stream>>>(x2, ln2w, ln2b, xn);
    // 7. fc1 GEMM + bias + GELU -> fc1h bf16 (qkv f32 dead)
    gemm_mfma<2><<<dim3(24, 32), 256, 0, stream>>>(xn, w_fc1, b_fc1, nullptr, fc1h, HID, 768);
    // 8. fc2 GEMM + bias + residual(x2) -> d_out f32
    gemm_mfma<3><<<dim3(6, 32), 256, 0, stream>>>(fc1h, w_fc2, b_fc2, x2, (float*)d_out, 768, 3072);
}

// Round 15
// 443.256 us; speedup vs baseline: 33.0902x; 1.1989x over previous
//
#include <hip/hip_runtime.h>
#include <hip/hip_bf16.h>

#define DIM 768
#define NH 12
#define BB 4
#define LL 1024
#define MM 4096
#define HID 3072

typedef short short8 __attribute__((ext_vector_type(8)));
typedef float f32x4 __attribute__((ext_vector_type(4)));

// f32 -> bf16 bits, round-to-nearest-even (finite inputs)
static __device__ __forceinline__ unsigned short f2bu(float f) {
    unsigned u = __float_as_uint(f);
    u += 0x7fffu + ((u >> 16) & 1u);
    return (unsigned short)(u >> 16);
}
static __device__ __forceinline__ float bu2f(unsigned short u) {
    return __uint_as_float((unsigned)u << 16);
}

// ---------------- LayerNorm: f32 row of 768 -> bf16(ushort) out ----------------
__global__ __launch_bounds__(256) void ln_kernel(const float* __restrict__ in,
                                                 const float* __restrict__ g,
                                                 const float* __restrict__ bta,
                                                 unsigned short* __restrict__ out) {
    __shared__ float red[8];
    int row = blockIdx.x;
    int tid = threadIdx.x;
    float v[3];
    float s = 0.f, s2 = 0.f;
#pragma unroll
    for (int i = 0; i < 3; ++i) {
        int c = tid + i*256;
        float x = in[(size_t)row*DIM + c];
        v[i] = x; s += x; s2 += x*x;
    }
#pragma unroll
    for (int off = 32; off; off >>= 1) { s += __shfl_down(s, off); s2 += __shfl_down(s2, off); }
    int wv = tid >> 6;
    if ((tid & 63) == 0) { red[wv] = s; red[4+wv] = s2; }
    __syncthreads();
    if (tid == 0) {
        float a = red[0]+red[1]+red[2]+red[3];
        float b = red[4]+red[5]+red[6]+red[7];
        red[0] = a * (1.f/DIM);
        red[4] = b * (1.f/DIM);
    }
    __syncthreads();
    float mu = red[0];
    float var = red[4] - mu*mu;
    float inv = rsqrtf(var + 1e-5f);
#pragma unroll
    for (int i = 0; i < 3; ++i) {
        int c = tid + i*256;
        out[(size_t)row*DIM + c] = f2bu((v[i]-mu)*inv*g[c] + bta[c]);
    }
}

// ---------------- MFMA NT GEMM: A (M x K) bf16-bits, W (N x K) f32 ----------------
// EPI: 0 = bias (f32 out), 2 = bias + exact GELU (bf16 out), 3 = bias + f32 residual (f32 out)
template<int EPI>
__global__ __launch_bounds__(256) void gemm_mfma(const unsigned short* __restrict__ A,
                                                 const float* __restrict__ W,
                                                 const float* __restrict__ bias,
                                                 const float* __restrict__ res,
                                                 void* __restrict__ out,
                                                 int N, int K) {
    __shared__ unsigned short As[128][40];   // pad 32->40: row stride 80 B (16B-mult, 2-way banks)
    __shared__ unsigned short Bs[128][40];
    int tid = threadIdx.x;
    int m0 = blockIdx.y * 128, n0 = blockIdx.x * 128;
    int wave = tid >> 6, lane = tid & 63;
    int wr = wave >> 1, wc = wave & 1;       // 2x2 wave grid, each 64x64
    int lr = lane & 15, kg = lane >> 4;
    f32x4 acc[4][4] = {};
    int ar = tid >> 2, ac = (tid & 3) * 8;   // staging: thread -> (row, 8-elem chunk)

    for (int kt = 0; kt < K; kt += 32) {
        __syncthreads();
        *(int4*)&As[ar][ac]    = *(const int4*)&A[(size_t)(m0+ar)*K + kt + ac];
        *(int4*)&As[ar+64][ac] = *(const int4*)&A[(size_t)(m0+ar+64)*K + kt + ac];
#pragma unroll
        for (int h = 0; h < 2; ++h) {
            int r = ar + h*64;
            const float* wp = &W[(size_t)(n0+r)*K + kt + ac];
            float4 w0 = *(const float4*)wp;
            float4 w1 = *(const float4*)(wp + 4);
            short8 wb;
            wb[0]=f2bu(w0.x); wb[1]=f2bu(w0.y); wb[2]=f2bu(w0.z); wb[3]=f2bu(w0.w);
            wb[4]=f2bu(w1.x); wb[5]=f2bu(w1.y); wb[6]=f2bu(w1.z); wb[7]=f2bu(w1.w);
            *(short8*)&Bs[r][ac] = wb;
        }
        __syncthreads();
        short8 af[4], bg[4];
#pragma unroll
        for (int m = 0; m < 4; ++m) af[m] = *(const short8*)&As[wr*64 + m*16 + lr][kg*8];
#pragma unroll
        for (int n = 0; n < 4; ++n) bg[n] = *(const short8*)&Bs[wc*64 + n*16 + lr][kg*8];
#pragma unroll
        for (int m = 0; m < 4; ++m)
#pragma unroll
            for (int n = 0; n < 4; ++n)
                acc[m][n] = __builtin_amdgcn_mfma_f32_16x16x32_bf16(af[m], bg[n], acc[m][n], 0, 0, 0);
    }

#pragma unroll
    for (int m = 0; m < 4; ++m) {
#pragma unroll
        for (int n = 0; n < 4; ++n) {
            int col = n0 + wc*64 + n*16 + lr;
            float bcol = bias[col];
#pragma unroll
            for (int j = 0; j < 4; ++j) {
                int row = m0 + wr*64 + m*16 + kg*4 + j;   // C/D: col=lane&15, row=(lane>>4)*4+j
                float v = acc[m][n][j] + bcol;
                if (EPI == 3) v += res[(size_t)row*N + col];
                if (EPI == 2) {
                    v = 0.5f*v*(1.f + erff(v*0.70710678118654752f));
                    ((unsigned short*)out)[(size_t)row*N + col] = f2bu(v);
                } else {
                    ((float*)out)[(size_t)row*N + col] = v;
                }
            }
        }
    }
}

// ---------------- qkv f32 -> per-head bf16 q/k/v with fused RoPE on q,k ----------------
// qb/kb/vb layout: [B][NH][L][64]
__global__ __launch_bounds__(256) void qkv_cvt(const float* __restrict__ qkv,
                                               unsigned short* __restrict__ qb,
                                               unsigned short* __restrict__ kb,
                                               unsigned short* __restrict__ vb) {
    int idx = blockIdx.x*256 + threadIdx.x;      // over 4096*1152 element-pairs
    int t  = idx / 1152;
    int cp = idx - t*1152;
    int col = cp*2;
    int s = col / 768;
    int wi = col - s*768;
    int n = wi >> 6, d = wi & 63;
    float2 v2 = *(const float2*)&qkv[(size_t)t*2304 + col];
    int l = t & (LL-1);
    if (s < 2) {
        int j = d >> 1;                          // pair index 0..31
        int pos = (j < 16) ? (l & 31) : (l >> 5);
        float freq = expf(-(float)(j & 15) * 0.0625f * 9.210340371976184f);
        float ang = (float)pos * freq;
        float sn, cs;
        sincosf(ang, &sn, &cs);
        float x0 = v2.x, x1 = v2.y;
        v2.x = x0*cs - x1*sn;
        v2.y = x0*sn + x1*cs;
    }
    unsigned short* dst = (s == 0) ? qb : (s == 1) ? kb : vb;
    int b = t >> 10;
    unsigned pk = (unsigned)f2bu(v2.x) | ((unsigned)f2bu(v2.y) << 16);
    *(unsigned*)&dst[((size_t)(b*NH + n)*LL + l)*64 + d] = pk;
}

// ---------------- MFMA flash attention: block = (b, head, 64 q-rows) ----------------
// v2: coalesced V^T gather (no LDS scatter), T14 prefetch, XCD-aware swizzle.
__global__ __launch_bounds__(256) void attn_mfma(const unsigned short* __restrict__ qb,
                                                 const unsigned short* __restrict__ kb,
                                                 const unsigned short* __restrict__ vb,
                                                 const float* __restrict__ relh,
                                                 const float* __restrict__ relw,
                                                 unsigned short* __restrict__ out) {
    __shared__ unsigned short Kb[64][72];     // K tile [k][d], row stride 144B
    __shared__ unsigned short Vt[64][72];     // V^T tile [d][k]
    __shared__ unsigned short Pb[4][16][72];  // per-wave P bounce [q][k]
    __shared__ float rbh[64][36];             // q x kh bias
    __shared__ float rbw[64][36];             // q x kw bias
    __shared__ float sl[128];                 // [0:64) per-tile scale, [64:128) 1/l

    // XCD-aware swizzle: 768 blocks = 8 XCDs x 96; each XCD gets 6 whole heads.
    int p = blockIdx.x + 16*(blockIdx.y + 12*blockIdx.z);
    int wg = (p & 7)*96 + (p >> 3);
    int qt = wg & 15, n = (wg >> 4) % 12, b = (wg >> 4) / 12;

    int tid = threadIdx.x;
    int w = tid >> 6, lane = tid & 63;
    int lr = lane & 15, kg = lane >> 4;
    size_t hb = ((size_t)b*NH + n) * (LL*64);

    const unsigned short* kbase = kb + hb;
    const unsigned short* vbase = vb + hb;

    // staging maps
    int sr = tid >> 3, sc8 = (tid & 7) * 8;   // K: rows sr, sr+32; 16B chunk sc8
    int vd = tid & 63, vco = tid >> 6;        // V^T: row d=vd; chunks vco, vco+4

    short8 kpre0, kpre1, vpre0, vpre1;
    auto load_tile = [&](int kt) {
        const unsigned short* kp = kbase + (size_t)(kt*64)*64;
        kpre0 = *(const short8*)(kp + (size_t)sr*64 + sc8);
        kpre1 = *(const short8*)(kp + (size_t)(sr+32)*64 + sc8);
        const unsigned short* vp = vbase + (size_t)(kt*64)*64;
#pragma unroll
        for (int i = 0; i < 8; ++i) vpre0[i] = (short)vp[(size_t)(vco*8 + i)*64 + vd];
#pragma unroll
        for (int i = 0; i < 8; ++i) vpre1[i] = (short)vp[(size_t)((vco+4)*8 + i)*64 + vd];
    };
    auto commit_tile = [&]() {
        *(short8*)&Kb[sr][sc8]        = kpre0;
        *(short8*)&Kb[sr+32][sc8]     = kpre1;
        *(short8*)&Vt[vd][vco*8]      = vpre0;
        *(short8*)&Vt[vd][vco*8 + 32] = vpre1;
    };

    load_tile(0);   // tile-0 global loads overlap the bias prologue below

    // --- rel-pos bias tables (vectorized loads; same index math as verified r10) ---
    {
        int q = tid >> 2, g = tid & 3;
        int qrow = qt*64 + q;
        int qh = qrow >> 5, qw = qrow & 31;
        const unsigned short* qr = qb + hb + (size_t)qrow*64;
        float ah[8] = {}, aw[8] = {};
#pragma unroll
        for (int d8 = 0; d8 < 8; ++d8) {
            short8 qv = *(const short8*)(qr + d8*8);
            float qf[8];
#pragma unroll
            for (int i2 = 0; i2 < 8; ++i2) qf[i2] = bu2f((unsigned short)qv[i2]);
#pragma unroll
            for (int i = 0; i < 8; ++i) {
                const float* rh = &relh[(size_t)(qh - (g*8+i) + 31)*64 + d8*8];
                const float* rw = &relw[(size_t)(qw - (g*8+i) + 31)*64 + d8*8];
                float4 h0 = *(const float4*)rh, h1 = *(const float4*)(rh+4);
                float4 w0 = *(const float4*)rw, w1 = *(const float4*)(rw+4);
                ah[i] += qf[0]*h0.x + qf[1]*h0.y + qf[2]*h0.z + qf[3]*h0.w
                       + qf[4]*h1.x + qf[5]*h1.y + qf[6]*h1.z + qf[7]*h1.w;
                aw[i] += qf[0]*w0.x + qf[1]*w0.y + qf[2]*w0.z + qf[3]*w0.w
                       + qf[4]*w1.x + qf[5]*w1.y + qf[6]*w1.z + qf[7]*w1.w;
            }
        }
#pragma unroll
        for (int i = 0; i < 8; ++i) { rbh[q][g*8+i] = ah[i]; rbw[q][g*8+i] = aw[i]; }
    }

    // --- Q fragments (B-operand; rows w*16+lr), in regs all kernel ---
    const unsigned short* qfr = qb + hb + (size_t)(qt*64 + w*16 + lr)*64;
    short8 qf0 = *(const short8*)(qfr + kg*8);
    short8 qf1 = *(const short8*)(qfr + 32 + kg*8);

    f32x4 o[4] = {};            // [dsub]; j <-> q = w*16+kg*4+j; col d = dsub*16+lr
    float mR = -1e30f, lR = 0.f;

    commit_tile();              // tile 0 -> LDS (vmcnt waited by compiler)
    __syncthreads();            // rb tables + tile 0 ready

    for (int kt = 0; kt < 16; ++kt) {
        if (kt < 15) load_tile(kt+1);   // T14: issue next-tile loads before compute

        // swapped QK^T: lane's scores have q = w*16+lr, k = ks*16+kg*4+j
        f32x4 st[4] = {};
#pragma unroll
        for (int ks = 0; ks < 4; ++ks) {
            short8 kf0 = *(const short8*)&Kb[ks*16 + lr][kg*8];
            short8 kf1 = *(const short8*)&Kb[ks*16 + lr][32 + kg*8];
            st[ks] = __builtin_amdgcn_mfma_f32_16x16x32_bf16(kf0, qf0, st[ks], 0, 0, 0);
            st[ks] = __builtin_amdgcn_mfma_f32_16x16x32_bf16(kf1, qf1, st[ks], 0, 0, 0);
        }
        int q = w*16 + lr;
        float rh0 = rbh[q][kt*2], rh1 = rbh[q][kt*2+1];
        f32x4 rw0 = *(const f32x4*)&rbw[q][kg*4];
        f32x4 rw1 = *(const f32x4*)&rbw[q][16 + kg*4];
        float tmax = -1e30f;
#pragma unroll
        for (int ks = 0; ks < 4; ++ks) {
            float rh = (ks < 2) ? rh0 : rh1;
#pragma unroll
            for (int j = 0; j < 4; ++j) {
                float sv = st[ks][j]*0.125f + rh + ((ks & 1) ? rw1[j] : rw0[j]);
                st[ks][j] = sv;
                tmax = fmaxf(tmax, sv);
            }
        }
        tmax = fmaxf(tmax, __shfl_xor(tmax, 16));
        tmax = fmaxf(tmax, __shfl_xor(tmax, 32));
        float mnew = fmaxf(mR, tmax);
        float sc = __expf(mR - mnew);
        float tsum = 0.f;
        unsigned pw0[4], pw1[4];
#pragma unroll
        for (int ks = 0; ks < 4; ++ks) {
            float e0 = __expf(st[ks][0]-mnew), e1 = __expf(st[ks][1]-mnew);
            float e2 = __expf(st[ks][2]-mnew), e3 = __expf(st[ks][3]-mnew);
            tsum += (e0+e1)+(e2+e3);
            pw0[ks] = (unsigned)f2bu(e0) | ((unsigned)f2bu(e1) << 16);
            pw1[ks] = (unsigned)f2bu(e2) | ((unsigned)f2bu(e3) << 16);
        }
        tsum += __shfl_xor(tsum, 16);
        tsum += __shfl_xor(tsum, 32);
        lR = lR*sc + tsum;
        mR = mnew;
        if (lane < 16) sl[w*16 + lr] = sc;
#pragma unroll
        for (int ks = 0; ks < 4; ++ks)
            *(uint2*)&Pb[w][lr][ks*16 + kg*4] = make_uint2(pw0[ks], pw1[ks]);
        // rescale O by per-row scale (j <-> q = w*16+kg*4+j)
        f32x4 sc4 = *(const f32x4*)&sl[w*16 + kg*4];
#pragma unroll
        for (int ds = 0; ds < 4; ++ds) o[ds] *= sc4;
        // PV: A = P (rows q via lr), B = V^T (rows d via lr)
        short8 pf0 = *(const short8*)&Pb[w][lr][kg*8];
        short8 pf1 = *(const short8*)&Pb[w][lr][32 + kg*8];
#pragma unroll
        for (int ds = 0; ds < 4; ++ds) {
            short8 vt0 = *(const short8*)&Vt[ds*16 + lr][kg*8];
            short8 vt1 = *(const short8*)&Vt[ds*16 + lr][32 + kg*8];
            o[ds] = __builtin_amdgcn_mfma_f32_16x16x32_bf16(pf0, vt0, o[ds], 0, 0, 0);
            o[ds] = __builtin_amdgcn_mfma_f32_16x16x32_bf16(pf1, vt1, o[ds], 0, 0, 0);
        }

        if (kt < 15) {
            __syncthreads();        // all reads of tile kt done
            commit_tile();          // tile kt+1 -> LDS
            __syncthreads();        // tile kt+1 visible
        }
    }

    if (lane < 16) sl[64 + w*16 + lr] = 1.f / lR;
    f32x4 il4 = *(const f32x4*)&sl[64 + w*16 + kg*4];
#pragma unroll
    for (int ds = 0; ds < 4; ++ds)
#pragma unroll
        for (int j = 0; j < 4; ++j) {
            size_t row = (size_t)b*LL + qt*64 + w*16 + kg*4 + j;
            out[row*DIM + n*64 + ds*16 + lr] = f2bu(o[ds][j] * il4[j]);
        }
}

extern "C" void kernel_launch(void* const* d_in, const int* in_sizes, int n_in,
                              void* d_out, int out_size, void* d_ws, size_t ws_size,
                              hipStream_t stream) {
    const float* x      = (const float*)d_in[0];
    const float* ln1w   = (const float*)d_in[1];
    const float* ln1b   = (const float*)d_in[2];
    const float* w_qkv  = (const float*)d_in[3];
    const float* b_qkv  = (const float*)d_in[4];
    const float* w_proj = (const float*)d_in[5];
    const float* b_proj = (const float*)d_in[6];
    const float* relh   = (const float*)d_in[7];
    const float* relw   = (const float*)d_in[8];
    const float* ln2w   = (const float*)d_in[9];
    const float* ln2b   = (const float*)d_in[10];
    const float* w_fc1  = (const float*)d_in[11];
    const float* b_fc1  = (const float*)d_in[12];
    const float* w_fc2  = (const float*)d_in[13];
    const float* b_fc2  = (const float*)d_in[14];

    char* ws = (char*)d_ws;
    unsigned short* xn   = (unsigned short*)(ws);              // [0, 6.29MB)
    float*          qkv  = (float*)(ws + 6291456);             // [6.29, 44.04MB)
    unsigned short* aout = (unsigned short*)(ws + 44040192);   // [44.04, 50.33MB)
    float*          x2   = (float*)(ws + 50331648);            // [50.33, 62.91MB)
    unsigned short* fc1h = (unsigned short*)(ws + 6291456);    // reuse qkv region
    unsigned short* qb   = (unsigned short*)(ws);              // xn dead after QKV GEMM
    unsigned short* kb   = (unsigned short*)(ws + 50331648);   // x2 region until step 5
    unsigned short* vb   = (unsigned short*)(ws + 56623104);

    // 1. LN1: x -> xn (bf16)
    ln_kernel<<<MM, 256, 0, stream>>>(x, ln1w, ln1b, xn);
    // 2. QKV GEMM -> qkv f32
    gemm_mfma<0><<<dim3(18, 32), 256, 0, stream>>>(xn, w_qkv, b_qkv, nullptr, qkv, 2304, 768);
    // 3. convert+rope: qkv f32 -> qb/kb/vb bf16
    qkv_cvt<<<18432, 256, 0, stream>>>(qkv, qb, kb, vb);
    // 4. MFMA flash attention -> aout bf16
    attn_mfma<<<dim3(16, NH, BB), 256, 0, stream>>>(qb, kb, vb, relh, relw, aout);
    // 5. proj GEMM + bias + residual(x) -> x2
    gemm_mfma<3><<<dim3(6, 32), 256, 0, stream>>>(aout, w_proj, b_proj, x, x2, 768, 768);
    // 6. LN2: x2 -> xn
    ln_kernel<<<MM, 256, 0, stream>>>(x2, ln2w, ln2b, xn);
    // 7. fc1 GEMM + bias + GELU -> fc1h bf16
    gemm_mfma<2><<<dim3(24, 32), 256, 0, stream>>>(xn, w_fc1, b_fc1, nullptr, fc1h, HID, 768);
    // 8. fc2 GEMM + bias + residual(x2) -> d_out f32
    gemm_mfma<3><<<dim3(6, 32), 256, 0, stream>>>(fc1h, w_fc2, b_fc2, x2, (float*)d_out, 768, 3072);
}